// Round 1
// baseline (421.852 us; speedup 1.0000x reference)
//
#include <hip/hip_runtime.h>
#include <stdint.h>

// T-structure as a signed permutation: for each (k,p) there is exactly one q
// with sign s such that T[k,p,q] = s. Transcribed from _TERMS.
__constant__ signed char QTAB[64] = {
    0,1,2,3,4,5,6,7,
    1,0,4,5,2,3,7,6,
    2,4,0,6,1,7,3,5,
    3,5,6,0,7,1,2,4,
    4,2,1,7,0,6,5,3,
    5,3,7,1,6,0,4,2,
    6,7,3,2,5,4,0,1,
    7,6,5,4,3,2,1,0};
__constant__ signed char SGN[64] = {
    1, 1, 1, 1,-1,-1,-1,-1,
    1, 1,-1, 1, 1,-1,-1,-1,
    1, 1, 1,-1,-1, 1, 1,-1,
    1,-1, 1, 1,-1,-1,-1, 1,
    1, 1,-1, 1, 1,-1, 1,-1,
    1,-1, 1, 1, 1, 1,-1,-1,
    1,-1,-1, 1,-1, 1, 1, 1,
    1, 1,-1, 1, 1,-1, 1, 1};

// Build Wl[o][iq][k] = wT[o,i,k,q] = sum_p T[k,p,q] * weight[o,i,p].
// Layout: contiguous 8 k-values per (o,iq) column -> s_load_dwordx8 in main.
// Every (k,q) pair has exactly one p (QTAB rows are permutations), so all
// 4096 entries are written exactly once: no zero-init, no races.
__global__ void clifford_prep(const float* __restrict__ weight,
                              float* __restrict__ Wl) {
    int t = threadIdx.x;
    for (int e = t; e < 4096; e += 256) {
        int o = e >> 9, i = (e >> 6) & 7, k = (e >> 3) & 7, p = e & 7;
        int q = (int)QTAB[k * 8 + p];
        float s = (float)SGN[k * 8 + p];
        Wl[(o * 64 + i * 8 + q) * 8 + k] = s * weight[(o * 8 + i) * 8 + p];
    }
}

// One thread per batch element: 64x64 matvec with wave-uniform weights.
// x (64 floats) lives in VGPRs; weights come in via scalar loads (uniform
// address) and feed v_fmac_f32 as the SGPR operand.
__global__ __launch_bounds__(256) void clifford_main(
    const float* __restrict__ x, const float* __restrict__ Wl,
    const float* __restrict__ bias, float* __restrict__ out, int nB) {
    int tid = blockIdx.x * 256 + threadIdx.x;
    int nthr = gridDim.x * 256;
    for (int b = tid; b < nB; b += nthr) {
        const float4* xp = (const float4*)(x + (size_t)b * 64);
        float xr[64];
#pragma unroll
        for (int j = 0; j < 16; ++j) {
            float4 v = xp[j];
            xr[4 * j + 0] = v.x;
            xr[4 * j + 1] = v.y;
            xr[4 * j + 2] = v.z;
            xr[4 * j + 3] = v.w;
        }
        float4* op = (float4*)(out + (size_t)b * 64);
#pragma unroll 1
        for (int o = 0; o < 8; ++o) {
            float acc[8];
#pragma unroll
            for (int k = 0; k < 8; ++k) acc[k] = bias[o * 8 + k];
            const float* Wr = Wl + o * 512;
#pragma unroll
            for (int iq = 0; iq < 64; ++iq) {
                float xv = xr[iq];
#pragma unroll
                for (int k = 0; k < 8; ++k)
                    acc[k] = fmaf(Wr[iq * 8 + k], xv, acc[k]);
            }
            float4 v0 = make_float4(acc[0], acc[1], acc[2], acc[3]);
            float4 v1 = make_float4(acc[4], acc[5], acc[6], acc[7]);
            op[o * 2 + 0] = v0;
            op[o * 2 + 1] = v1;
        }
    }
}

extern "C" void kernel_launch(void* const* d_in, const int* in_sizes, int n_in,
                              void* d_out, int out_size, void* d_ws,
                              size_t ws_size, hipStream_t stream) {
    const float* x = (const float*)d_in[0];
    const float* weight = (const float*)d_in[1];
    const float* bias = (const float*)d_in[2];
    float* out = (float*)d_out;
    float* Wl = (float*)d_ws;  // 4096 floats = 16 KB scratch

    int nB = in_sizes[0] / 64;  // 4096*512 batch elements

    hipLaunchKernelGGL(clifford_prep, dim3(1), dim3(256), 0, stream, weight,
                       Wl);
    int blocks = (nB + 255) / 256;
    hipLaunchKernelGGL(clifford_main, dim3(blocks), dim3(256), 0, stream, x,
                       Wl, bias, out, nB);
}

// Round 2
// 245.126 us; speedup vs baseline: 1.7210x; 1.7210x over previous
//
#include <hip/hip_runtime.h>
#include <stdint.h>

// T-structure as a signed permutation: for each (k,p) there is exactly one q
// with sign s such that T[k,p,q] = s. Transcribed from _TERMS.
__constant__ signed char QTAB[64] = {
    0,1,2,3,4,5,6,7,
    1,0,4,5,2,3,7,6,
    2,4,0,6,1,7,3,5,
    3,5,6,0,7,1,2,4,
    4,2,1,7,0,6,5,3,
    5,3,7,1,6,0,4,2,
    6,7,3,2,5,4,0,1,
    7,6,5,4,3,2,1,0};
__constant__ signed char SGN[64] = {
    1, 1, 1, 1,-1,-1,-1,-1,
    1, 1,-1, 1, 1,-1,-1,-1,
    1, 1, 1,-1,-1, 1, 1,-1,
    1,-1, 1, 1,-1,-1,-1, 1,
    1, 1,-1, 1, 1,-1, 1,-1,
    1,-1, 1, 1, 1, 1,-1,-1,
    1,-1,-1, 1,-1, 1, 1, 1,
    1, 1,-1, 1, 1,-1, 1, 1};

// W2[iq][m] such that out[b][m] = sum_iq x[b][iq] * W2[iq][m]  (m = o*8+k,
// iq = i*8+q). Each entry written exactly once (QTAB rows are permutations).
__global__ void clifford_prep(const float* __restrict__ weight,
                              float* __restrict__ W2) {
    int t = threadIdx.x;
    for (int e = t; e < 4096; e += 256) {
        int o = e >> 9, i = (e >> 6) & 7, k = (e >> 3) & 7, p = e & 7;
        int q = (int)QTAB[k * 8 + p];
        float s = (float)SGN[k * 8 + p];
        W2[((i * 8 + q) * 64) + (o * 8 + k)] = s * weight[(o * 8 + i) * 8 + p];
    }
}

#define LSTR 33  // LDS row stride in floats (odd -> 2-way banks = free)

// One wave = 64 batch elements. Global traffic in 128-B contiguous segments;
// LDS (wave-private, no barriers) does the row<->lane transpose in 32-column
// halves to keep LDS at 8.45 KB/wave. Weights are wave-uniform -> SGPRs.
__global__ __launch_bounds__(256) void clifford_main(
    const float* __restrict__ x, const float* __restrict__ W,
    const float* __restrict__ bias, float* __restrict__ out, int nB) {
    __shared__ float lds[4][64 * LSTR];
    const int wave = threadIdx.x >> 6;
    const int lane = threadIdx.x & 63;
    float* Lw = lds[wave];
    const long long base = ((long long)blockIdx.x * 4 + wave) * 64;
    if (base >= nB) return;
    const float* xt = x + base * 64;
    float* ot = out + base * 64;
    const int r8 = lane >> 3;        // which 8-row group member
    const int c8 = (lane & 7) * 4;   // column quad within the 32-col half

    // ---- load half 0 (cols 0..31 of 64 rows): 8x 128-B segments / instr ----
    float4 r0[8];
#pragma unroll
    for (int i = 0; i < 8; ++i)
        r0[i] = *(const float4*)(xt + (size_t)(r8 + 8 * i) * 64 + c8);
#pragma unroll
    for (int i = 0; i < 8; ++i) {
        int b = r8 + 8 * i;
        Lw[b * LSTR + c8 + 0] = r0[i].x;
        Lw[b * LSTR + c8 + 1] = r0[i].y;
        Lw[b * LSTR + c8 + 2] = r0[i].z;
        Lw[b * LSTR + c8 + 3] = r0[i].w;
    }

    // ---- prefetch half 1 into registers (overlaps compute of half 0) ----
    float4 r1[8];
#pragma unroll
    for (int i = 0; i < 8; ++i)
        r1[i] = *(const float4*)(xt + (size_t)(r8 + 8 * i) * 64 + 32 + c8);

    // ---- accumulators: m = o*8+k is flat output order; bias is flat too ----
    float acc[64];
#pragma unroll
    for (int m = 0; m < 64; ++m) acc[m] = bias[m];

    // ---- compute half 0 ----
#pragma unroll 2
    for (int iq = 0; iq < 32; ++iq) {
        float xv = Lw[lane * LSTR + iq];
        const float* Wr = W + iq * 64;  // wave-uniform -> s_load
#pragma unroll
        for (int m = 0; m < 64; ++m) acc[m] = fmaf(Wr[m], xv, acc[m]);
    }

    // ---- stage half 1 ----
#pragma unroll
    for (int i = 0; i < 8; ++i) {
        int b = r8 + 8 * i;
        Lw[b * LSTR + c8 + 0] = r1[i].x;
        Lw[b * LSTR + c8 + 1] = r1[i].y;
        Lw[b * LSTR + c8 + 2] = r1[i].z;
        Lw[b * LSTR + c8 + 3] = r1[i].w;
    }

    // ---- compute half 1 ----
#pragma unroll 2
    for (int iq = 0; iq < 32; ++iq) {
        float xv = Lw[lane * LSTR + iq];
        const float* Wr = W + (32 + iq) * 64;
#pragma unroll
        for (int m = 0; m < 64; ++m) acc[m] = fmaf(Wr[m], xv, acc[m]);
    }

    // ---- output: transpose through LDS in two 32-col halves, store 128-B
    //      segments ----
#pragma unroll
    for (int mh = 0; mh < 2; ++mh) {
#pragma unroll
        for (int m = 0; m < 32; ++m) Lw[lane * LSTR + m] = acc[mh * 32 + m];
#pragma unroll
        for (int i = 0; i < 8; ++i) {
            int b = r8 + 8 * i;
            float4 v;
            v.x = Lw[b * LSTR + c8 + 0];
            v.y = Lw[b * LSTR + c8 + 1];
            v.z = Lw[b * LSTR + c8 + 2];
            v.w = Lw[b * LSTR + c8 + 3];
            *(float4*)(ot + (size_t)b * 64 + mh * 32 + c8) = v;
        }
    }
}

extern "C" void kernel_launch(void* const* d_in, const int* in_sizes, int n_in,
                              void* d_out, int out_size, void* d_ws,
                              size_t ws_size, hipStream_t stream) {
    const float* x = (const float*)d_in[0];
    const float* weight = (const float*)d_in[1];
    const float* bias = (const float*)d_in[2];
    float* out = (float*)d_out;
    float* W2 = (float*)d_ws;  // 4096 floats = 16 KB scratch

    int nB = in_sizes[0] / 64;  // 4096*512 batch elements

    hipLaunchKernelGGL(clifford_prep, dim3(1), dim3(256), 0, stream, weight,
                       W2);
    int nTiles = (nB + 63) / 64;          // 64 batch elements per wave
    int blocks = (nTiles + 3) / 4;        // 4 waves per block
    hipLaunchKernelGGL(clifford_main, dim3(blocks), dim3(256), 0, stream, x,
                       W2, bias, out, nB);
}